// Round 6
// baseline (305.186 us; speedup 1.0000x reference)
//
#include <hip/hip_runtime.h>
#include <hip/hip_fp16.h>

#define L_SEQ 4096
#define SBK 32

typedef _Float16 f16x8 __attribute__((ext_vector_type(8)));
typedef _Float16 f16x4 __attribute__((ext_vector_type(4)));
typedef float f32x4 __attribute__((ext_vector_type(4)));

typedef __attribute__((address_space(3))) void lds_void;
typedef __attribute__((address_space(1))) void glob_void;
__device__ __forceinline__ void gload16(const _Float16* g, _Float16* l) {
  __builtin_amdgcn_global_load_lds((const glob_void*)g, (lds_void*)l, 16, 0, 0);
}

// ---------------- converts ----------------
__global__ __launch_bounds__(256)
void cvt_split(const float* __restrict__ in, _Float16* __restrict__ hi,
               _Float16* __restrict__ lo) {
  int i = blockIdx.x * 256 + threadIdx.x;
  float4 v = ((const float4*)in)[i];
  f16x4 h, l;
  h[0] = (_Float16)v.x; h[1] = (_Float16)v.y;
  h[2] = (_Float16)v.z; h[3] = (_Float16)v.w;
  l[0] = (_Float16)((v.x - (float)h[0]) * 2048.0f);
  l[1] = (_Float16)((v.y - (float)h[1]) * 2048.0f);
  l[2] = (_Float16)((v.z - (float)h[2]) * 2048.0f);
  l[3] = (_Float16)((v.w - (float)h[3]) * 2048.0f);
  *(f16x4*)(hi + (size_t)i * 4) = h;
  *(f16x4*)(lo + (size_t)i * 4) = l;
}

__global__ __launch_bounds__(256)
void cvt_tr_split(const float* __restrict__ W, _Float16* __restrict__ WTh,
                  _Float16* __restrict__ WTl) {
  __shared__ _Float16 th[32][33];
  __shared__ _Float16 tl[32][33];
  const int bx = blockIdx.x * 32, by = blockIdx.y * 32;
  const int tx = threadIdx.x & 31, ty = threadIdx.x >> 5;
  #pragma unroll
  for (int i = ty; i < 32; i += 8) {
    float w = W[(size_t)(by + i) * 1024 + bx + tx];
    _Float16 h = (_Float16)w;
    th[i][tx] = h;
    tl[i][tx] = (_Float16)((w - (float)h) * 2048.0f);
  }
  __syncthreads();
  #pragma unroll
  for (int i = ty; i < 32; i += 8) {
    WTh[(size_t)(bx + i) * 1024 + by + tx] = th[tx][i];
    WTl[(size_t)(bx + i) * 1024 + by + tx] = tl[tx][i];
  }
}

__global__ __launch_bounds__(256)
void cvt_tr_f16(const float* __restrict__ W, _Float16* __restrict__ WT) {
  __shared__ _Float16 tile[32][33];
  const int bx = blockIdx.x * 32, by = blockIdx.y * 32;
  const int tx = threadIdx.x & 31, ty = threadIdx.x >> 5;
  #pragma unroll
  for (int i = ty; i < 32; i += 8)
    tile[i][tx] = (_Float16)W[(size_t)(by + i) * 1024 + bx + tx];
  __syncthreads();
  #pragma unroll
  for (int i = ty; i < 32; i += 8)
    WT[(size_t)(bx + i) * 1024 + by + tx] = tile[tx][i];
}

// ---------------- split-f16 MFMA GEMM, 2-phase dbuf (fp32-accurate hash path) -------
// C[M,Nn] = (Ahi+Alo/2048)[M,K] * (Bhi+Blo/2048)^T[Nn,K], scatter f32 [n][l][d]
// BK=32, buffers [2][128][32], 64 KB LDS, 1 barrier per K-step.
__global__ __launch_bounds__(256)
void gemm_f16_split(const _Float16* __restrict__ Ahi, const _Float16* __restrict__ Alo,
                    const _Float16* __restrict__ Bhi, const _Float16* __restrict__ Blo,
                    float* __restrict__ C, int M, int K, int Nn) {
  __shared__ _Float16 Ash[2][128 * SBK];
  __shared__ _Float16 Asl[2][128 * SBK];
  __shared__ _Float16 Bsh[2][128 * SBK];
  __shared__ _Float16 Bsl[2][128 * SBK];
  const int tid = threadIdx.x;
  const int lane = tid & 63, wid = tid >> 6;
  const int wr = wid >> 1, wc = wid & 1;
  const int row0 = blockIdx.y * 128, col0 = blockIdx.x * 128;

  f32x4 acch[4][4], accl[4][4];
  #pragma unroll
  for (int i = 0; i < 4; ++i)
    #pragma unroll
    for (int j = 0; j < 4; ++j) {
      acch[i][j] = (f32x4){0.f, 0.f, 0.f, 0.f};
      accl[i][j] = (f32x4){0.f, 0.f, 0.f, 0.f};
    }

  // staging: wave stages rows [wid*32, wid*32+32), 2 issues of 16 rows per stream.
  // lane -> row = l>>2, 16B-chunk = (l&3) ^ ((l>>3)&3)  (source pre-swizzle)
  const int srcRow = lane >> 2;
  const int srcColH = ((lane & 3) ^ ((lane >> 3) & 3)) * 8;   // halves
  const size_t aoff = (size_t)(row0 + wid * 32 + srcRow) * K + srcColH;
  const size_t boff = (size_t)(col0 + wid * 32 + srcRow) * K + srcColH;
  const int ld0 = (wid * 32) * SBK;        // halves
  const int ld1 = (wid * 32 + 16) * SBK;

  const int fr = lane & 15, g = lane >> 4;
  const int koH = (g ^ ((fr >> 1) & 3)) * 8;   // read swizzle (same involution)

  // prologue: stage t=0 into buf 0
  {
    const size_t k0 = 0;
    gload16(Ahi + aoff + k0, &Ash[0][ld0]);
    gload16(Ahi + aoff + 16 * (size_t)K + k0, &Ash[0][ld1]);
    gload16(Alo + aoff + k0, &Asl[0][ld0]);
    gload16(Alo + aoff + 16 * (size_t)K + k0, &Asl[0][ld1]);
    gload16(Bhi + boff + k0, &Bsh[0][ld0]);
    gload16(Bhi + boff + 16 * (size_t)K + k0, &Bsh[0][ld1]);
    gload16(Blo + boff + k0, &Bsl[0][ld0]);
    gload16(Blo + boff + 16 * (size_t)K + k0, &Bsl[0][ld1]);
  }
  __syncthreads();

  const int NT = K / SBK;   // 32
  for (int t = 0; t < NT; ++t) {
    const int cur = t & 1, nxt = cur ^ 1;
    if (t + 1 < NT) {   // issue next-tile loads BEFORE compute (overlap)
      const size_t k0 = (size_t)(t + 1) * SBK;
      gload16(Ahi + aoff + k0, &Ash[nxt][ld0]);
      gload16(Ahi + aoff + 16 * (size_t)K + k0, &Ash[nxt][ld1]);
      gload16(Alo + aoff + k0, &Asl[nxt][ld0]);
      gload16(Alo + aoff + 16 * (size_t)K + k0, &Asl[nxt][ld1]);
      gload16(Bhi + boff + k0, &Bsh[nxt][ld0]);
      gload16(Bhi + boff + 16 * (size_t)K + k0, &Bsh[nxt][ld1]);
      gload16(Blo + boff + k0, &Bsl[nxt][ld0]);
      gload16(Blo + boff + 16 * (size_t)K + k0, &Bsl[nxt][ld1]);
    }
    f16x8 ah[4], al[4], bh[4], bl[4];
    #pragma unroll
    for (int fi = 0; fi < 4; ++fi) {
      ah[fi] = *(const f16x8*)&Ash[cur][(wr * 64 + fi * 16 + fr) * SBK + koH];
      al[fi] = *(const f16x8*)&Asl[cur][(wr * 64 + fi * 16 + fr) * SBK + koH];
    }
    #pragma unroll
    for (int fj = 0; fj < 4; ++fj) {
      bh[fj] = *(const f16x8*)&Bsh[cur][(wc * 64 + fj * 16 + fr) * SBK + koH];
      bl[fj] = *(const f16x8*)&Bsl[cur][(wc * 64 + fj * 16 + fr) * SBK + koH];
    }
    #pragma unroll
    for (int fi = 0; fi < 4; ++fi)
      #pragma unroll
      for (int fj = 0; fj < 4; ++fj) {
        acch[fi][fj] = __builtin_amdgcn_mfma_f32_16x16x32_f16(
            ah[fi], bh[fj], acch[fi][fj], 0, 0, 0);
        accl[fi][fj] = __builtin_amdgcn_mfma_f32_16x16x32_f16(
            al[fi], bh[fj], accl[fi][fj], 0, 0, 0);
        accl[fi][fj] = __builtin_amdgcn_mfma_f32_16x16x32_f16(
            ah[fi], bl[fj], accl[fi][fj], 0, 0, 0);
      }
    __syncthreads();   // drains vmcnt (next tile resident) + protects cur reuse
  }

  #pragma unroll
  for (int fi = 0; fi < 4; ++fi) {
    #pragma unroll
    for (int fj = 0; fj < 4; ++fj) {
      const int col = col0 + wc * 64 + fj * 16 + fr;
      #pragma unroll
      for (int r = 0; r < 4; ++r) {
        const int row = row0 + wr * 64 + fi * 16 + g * 4 + r;
        int b = row >> 12, l = row & 4095;
        int h = col >> 6, d = col & 63;
        C[(((size_t)(b * 16 + h) * L_SEQ) + l) * 64 + d] =
            acch[fi][fj][r] + accl[fi][fj][r] * (1.0f / 2048.0f);
      }
    }
  }
}

// ---------------- f16 MFMA GEMM, 2-phase dbuf: C = A * BT^T ----------------
// MODE 0: C row-major f32; MODE 1: scatter f16 to [n][l][d]
template<int MODE>
__global__ __launch_bounds__(256)
void gemm_f16(const _Float16* __restrict__ A, const _Float16* __restrict__ BT,
              float* __restrict__ C, int M, int K, int Nn) {
  __shared__ _Float16 As[2][128 * 64];
  __shared__ _Float16 Bs[2][128 * 64];
  const int tid = threadIdx.x;
  const int lane = tid & 63, wid = tid >> 6;
  const int wr = wid >> 1, wc = wid & 1;
  const int row0 = blockIdx.y * 128, col0 = blockIdx.x * 128;

  f32x4 acc[4][4];
  #pragma unroll
  for (int i = 0; i < 4; ++i)
    #pragma unroll
    for (int j = 0; j < 4; ++j)
      acc[i][j] = (f32x4){0.f, 0.f, 0.f, 0.f};

  const int srow = (lane >> 3);
  const int scol = ((lane & 7) ^ srow) * 8;
  const _Float16* ga = A + (size_t)(row0 + wid * 32 + srow) * K + scol;
  const _Float16* gb = BT + (size_t)(col0 + wid * 32 + srow) * K + scol;
  const int lbase = (wid * 32) * 64;
  const int fr = lane & 15, g = lane >> 4;

  {  // prologue stage t=0
    #pragma unroll
    for (int i = 0; i < 4; ++i) {
      gload16(ga + (size_t)i * 8 * K, &As[0][lbase + i * 8 * 64]);
      gload16(gb + (size_t)i * 8 * K, &Bs[0][lbase + i * 8 * 64]);
    }
  }
  __syncthreads();

  const int NT = K / 64;   // 16
  for (int t = 0; t < NT; ++t) {
    const int cur = t & 1, nxt = cur ^ 1;
    if (t + 1 < NT) {
      const size_t k0 = (size_t)(t + 1) * 64;
      #pragma unroll
      for (int i = 0; i < 4; ++i) {
        gload16(ga + k0 + (size_t)i * 8 * K, &As[nxt][lbase + i * 8 * 64]);
        gload16(gb + k0 + (size_t)i * 8 * K, &Bs[nxt][lbase + i * 8 * 64]);
      }
    }
    f16x8 af[4][2], bf[4][2];
    #pragma unroll
    for (int fi = 0; fi < 4; ++fi) {
      const int ra = (wr * 64 + fi * 16 + fr) * 64;
      const int rb = (wc * 64 + fi * 16 + fr) * 64;
      #pragma unroll
      for (int ks = 0; ks < 2; ++ks) {
        const int ko = (ks * 32 + g * 8) ^ ((fr & 7) * 8);
        af[fi][ks] = *(const f16x8*)(&As[cur][ra + ko]);
        bf[fi][ks] = *(const f16x8*)(&Bs[cur][rb + ko]);
      }
    }
    #pragma unroll
    for (int ks = 0; ks < 2; ++ks)
      #pragma unroll
      for (int fi = 0; fi < 4; ++fi)
        #pragma unroll
        for (int fj = 0; fj < 4; ++fj)
          acc[fi][fj] = __builtin_amdgcn_mfma_f32_16x16x32_f16(
              af[fi][ks], bf[fj][ks], acc[fi][fj], 0, 0, 0);
    __syncthreads();
  }

  _Float16* Ch = (_Float16*)C;
  #pragma unroll
  for (int fi = 0; fi < 4; ++fi) {
    #pragma unroll
    for (int fj = 0; fj < 4; ++fj) {
      const int col = col0 + wc * 64 + fj * 16 + fr;
      #pragma unroll
      for (int r = 0; r < 4; ++r) {
        const int row = row0 + wr * 64 + fi * 16 + g * 4 + r;
        if (MODE == 0) {
          C[(size_t)row * Nn + col] = acc[fi][fj][r];
        } else {
          int b = row >> 12, l = row & 4095;
          int h = col >> 6, d = col & 63;
          Ch[(((size_t)(b * 16 + h) * L_SEQ) + l) * 64 + d] = (_Float16)acc[fi][fj][r];
        }
      }
    }
  }
}

// ---------------- LSH hashing (fp32 exact) ----------------
__global__ __launch_bounds__(256)
void lsh_hash(const float* __restrict__ qk, const float* __restrict__ rot,
              unsigned char* __restrict__ bucket) {
  __shared__ float rots[4096];
  const int tid = threadIdx.x;
  for (int idx = tid; idx < 4096; idx += 256) rots[idx] = rot[idx];
  __syncthreads();
  const int n = blockIdx.y;
  const int l = blockIdx.x * 256 + tid;
  const float4* q4p = (const float4*)(qk + ((size_t)n * L_SEQ + l) * 64);
  float qr[64];
  #pragma unroll
  for (int t4 = 0; t4 < 16; ++t4) {
    float4 t = q4p[t4];
    qr[t4 * 4 + 0] = t.x; qr[t4 * 4 + 1] = t.y;
    qr[t4 * 4 + 2] = t.z; qr[t4 * 4 + 3] = t.w;
  }
  #pragma unroll 1
  for (int hr = 0; hr < 2; ++hr) {
    float val[32];
    #pragma unroll
    for (int rb = 0; rb < 32; ++rb) val[rb] = 0.f;
    #pragma unroll
    for (int d = 0; d < 64; ++d) {
      float qd = qr[d];
      const float* rp = &rots[d * 64 + hr * 32];
      #pragma unroll
      for (int rb = 0; rb < 32; ++rb) val[rb] += qd * rp[rb];
    }
    float best = val[0]; int bidx = 0;
    #pragma unroll
    for (int k = 1; k < 32; ++k) { if (val[k] > best) { best = val[k]; bidx = k; } }
    #pragma unroll
    for (int k = 0; k < 32; ++k) { float vn = -val[k]; if (vn > best) { best = vn; bidx = 32 + k; } }
    bucket[((size_t)n * 2 + hr) * L_SEQ + l] = (unsigned char)bidx;
  }
}

// ---------------- parallel stable counting sort per (n, round) ----------------
__global__ __launch_bounds__(256)
void lsh_sort(const unsigned char* __restrict__ bucket, unsigned int* __restrict__ st) {
  __shared__ unsigned short cnt[64][257];
  __shared__ unsigned int bstart[64];
  __shared__ unsigned char bkt[4096];
  const int nr = blockIdx.x;
  const int tid = threadIdx.x;
  const unsigned char* bsrc = bucket + (size_t)nr * L_SEQ;
  for (int i = tid; i < 1024; i += 256)
    ((unsigned int*)bkt)[i] = ((const unsigned int*)bsrc)[i];
  #pragma unroll
  for (int b = 0; b < 64; ++b) cnt[b][tid] = 0;
  __syncthreads();
  uint4 wv = ((const uint4*)bkt)[tid];
  unsigned int wsg[4] = {wv.x, wv.y, wv.z, wv.w};
  #pragma unroll
  for (int k = 0; k < 16; ++k) {
    int b = (wsg[k >> 2] >> ((k & 3) * 8)) & 63;
    cnt[b][tid]++;
  }
  __syncthreads();
  if (tid < 64) {
    const int b = tid;
    unsigned int run = 0;
    for (int t = 0; t < 256; ++t) {
      unsigned int c = cnt[b][t];
      cnt[b][t] = (unsigned short)run;
      run += c;
    }
    unsigned int incl = run;
    #pragma unroll
    for (int off = 1; off < 64; off <<= 1) {
      unsigned int up = (unsigned int)__shfl_up((int)incl, off);
      if (tid >= off) incl += up;
    }
    bstart[b] = incl - run;
  }
  __syncthreads();
  const int n = nr >> 1, r = nr & 1;
  unsigned int* dst = st + (size_t)n * 8192 + (size_t)r * 4096;
  #pragma unroll
  for (int k = 0; k < 16; ++k) {
    int b = (wsg[k >> 2] >> ((k & 3) * 8)) & 63;
    unsigned int idx = bstart[b] + cnt[b][tid];
    cnt[b][tid]++;
    dst[idx] = (unsigned int)(tid * 16 + k);
  }
}

// ---------------- MFMA chunked local attention ----------------
__global__ __launch_bounds__(256)
void lsh_attn_mfma(const float* __restrict__ qkf, const _Float16* __restrict__ vh,
                   const unsigned int* __restrict__ st,
                   _Float16* __restrict__ o, float* __restrict__ logits) {
  __shared__ _Float16 Kl[128 * 64];
  __shared__ _Float16 Vt[64 * 128];
  __shared__ _Float16 Pl[64 * 128];
  __shared__ float rsqs[128];
  __shared__ float partial[256];
  __shared__ int posl[128];

  const int tid = threadIdx.x;
  const int lane = tid & 63, wid = tid >> 6;
  const int fr = lane & 15, g = lane >> 4;
  const int c = blockIdx.x, n = blockIdx.y;
  const int cprev = (c + 127) & 127;

  if (tid < 128) {
    int p = (tid < 64) ? (c * 64 + tid) : (cprev * 64 + (tid - 64));
    posl[tid] = (int)st[(size_t)n * 8192 + p];
  }
  __syncthreads();

  {
    const int j = tid >> 1, h = tid & 1;
    const int gpos = posl[j];
    const float4* srcK = (const float4*)(qkf + ((size_t)n * L_SEQ + gpos) * 64 + h * 32);
    const f16x8* srcV = (const f16x8*)(vh + ((size_t)n * L_SEQ + gpos) * 64 + h * 32);
    float ss = 0.f;
    #pragma unroll
    for (int i = 0; i < 4; ++i) {
      float4 f0 = srcK[2 * i], f1 = srcK[2 * i + 1];
      ss += f0.x * f0.x + f0.y * f0.y + f0.z * f0.z + f0.w * f0.w;
      ss += f1.x * f1.x + f1.y * f1.y + f1.z * f1.z + f1.w * f1.w;
      f16x8 kv;
      kv[0] = (_Float16)f0.x; kv[1] = (_Float16)f0.y;
      kv[2] = (_Float16)f0.z; kv[3] = (_Float16)f0.w;
      kv[4] = (_Float16)f1.x; kv[5] = (_Float16)f1.y;
      kv[6] = (_Float16)f1.z; kv[7] = (_Float16)f1.w;
      int ch = h * 4 + i;
      *(f16x8*)(&Kl[j * 64 + ((ch ^ (j & 7)) * 8)]) = kv;
      f16x8 vv4 = srcV[i];
      #pragma unroll
      for (int e = 0; e < 8; ++e) {
        int d = h * 32 + i * 8 + e;
        Vt[d * 128 + (j ^ ((d & 7) << 3))] = vv4[e];
      }
    }
    partial[tid] = ss;
  }
  __syncthreads();
  if (tid < 128)
    rsqs[tid] = rsqrtf(fmaxf(partial[tid * 2] + partial[tid * 2 + 1], 1e-12f));
  __syncthreads();

  const int q0 = wid * 16;
  f32x4 acc[8];
  #pragma unroll
  for (int t = 0; t < 8; ++t) acc[t] = (f32x4){0.f, 0.f, 0.f, 0.f};
  f16x8 aq[2];
  #pragma unroll
  for (int ks = 0; ks < 2; ++ks)
    aq[ks] = *(const f16x8*)&Kl[(q0 + fr) * 64 + (((ks * 4 + g) ^ (fr & 7)) * 8)];
  #pragma unroll
  for (int t = 0; t < 8; ++t) {
    #pragma unroll
    for (int ks = 0; ks < 2; ++ks) {
      f16x8 bk = *(const f16x8*)&Kl[(t * 16 + fr) * 64 + (((ks * 4 + g) ^ (fr & 7)) * 8)];
      acc[t] = __builtin_amdgcn_mfma_f32_16x16x32_f16(aq[ks], bk, acc[t], 0, 0, 0);
    }
  }

  float sc[8][4];
  int pq[4];
  #pragma unroll
  for (int r = 0; r < 4; ++r) pq[r] = posl[q0 + g * 4 + r];
  #pragma unroll
  for (int t = 0; t < 8; ++t) {
    float rs = rsqs[t * 16 + fr] * 0.125f;
    int pk = posl[t * 16 + fr];
    #pragma unroll
    for (int r = 0; r < 4; ++r) {
      float v_ = acc[t][r] * rs;
      if (pq[r] == pk) v_ += -1e5f;
      sc[t][r] = v_;
    }
  }
  float lsef[4];
  #pragma unroll
  for (int r = 0; r < 4; ++r) {
    float m = sc[0][r];
    #pragma unroll
    for (int t = 1; t < 8; ++t) m = fmaxf(m, sc[t][r]);
    #pragma unroll
    for (int off = 1; off < 16; off <<= 1) m = fmaxf(m, __shfl_xor(m, off, 64));
    float s = 0.f;
    #pragma unroll
    for (int t = 0; t < 8; ++t) { float e = __expf(sc[t][r] - m); sc[t][r] = e; s += e; }
    #pragma unroll
    for (int off = 1; off < 16; off <<= 1) s += __shfl_xor(s, off, 64);
    lsef[r] = m + __logf(s);
    float f = 1.0f / s;
    #pragma unroll
    for (int t = 0; t < 8; ++t) sc[t][r] *= f;
  }

  #pragma unroll
  for (int t = 0; t < 8; ++t)
    #pragma unroll
    for (int r = 0; r < 4; ++r) {
      int q = q0 + g * 4 + r;
      Pl[q * 128 + ((t * 16 + fr) ^ ((q & 7) << 3))] = (_Float16)sc[t][r];
    }
  const int rr = c >> 6;
  if (fr == 0) {
    #pragma unroll
    for (int r = 0; r < 4; ++r) {
      int q = q0 + g * 4 + r;
      logits[((size_t)n * 2 + rr) * L_SEQ + posl[q]] = lsef[r];
    }
  }

  f32x4 acc2[4];
  #pragma unroll
  for (int td = 0; td < 4; ++td) acc2[td] = (f32x4){0.f, 0.f, 0.f, 0.f};
  #pragma unroll
  for (int s = 0; s < 4; ++s) {
    f16x8 ap = *(const f16x8*)&Pl[(q0 + fr) * 128 + (((s * 4 + g) ^ (fr & 7)) * 8)];
    #pragma unroll
    for (int td = 0; td < 4; ++td) {
      f16x8 bv = *(const f16x8*)&Vt[(td * 16 + fr) * 128 + (((s * 4 + g) ^ (fr & 7)) * 8)];
      acc2[td] = __builtin_amdgcn_mfma_f32_16x16x32_f16(ap, bv, acc2[td], 0, 0, 0);
    }
  }
  #pragma unroll
  for (int r = 0; r < 4; ++r) {
    int q = q0 + g * 4 + r;
    size_t base = (((size_t)n * 2 + rr) * L_SEQ + posl[q]) * 64;
    #pragma unroll
    for (int td = 0; td < 4; ++td)
      o[base + td * 16 + fr] = (_Float16)acc2[td][r];
  }
}

// ---------------- combine hash rounds -> f16 att [8192][1024] ----------------
__global__ __launch_bounds__(256)
void lsh_combine(const __half* __restrict__ o, const float* __restrict__ logits,
                 _Float16* __restrict__ attf) {
  size_t gid = (size_t)blockIdx.x * 256 + threadIdx.x;
  int q4 = (int)(gid & 15);
  size_t nl = gid >> 4;
  int n = (int)(nl >> 12), l = (int)(nl & 4095);
  float l0 = logits[((size_t)n * 2 + 0) * L_SEQ + l];
  float l1 = logits[((size_t)n * 2 + 1) * L_SEQ + l];
  float m = fmaxf(l0, l1);
  float e0 = __expf(l0 - m), e1 = __expf(l1 - m);
  float inv = 1.0f / (e0 + e1);
  float w0 = e0 * inv, w1 = e1 * inv;
  const __half2* r0 = (const __half2*)(o + (((size_t)n * 2 + 0) * L_SEQ + l) * 64) + q4 * 2;
  const __half2* r1 = (const __half2*)(o + (((size_t)n * 2 + 1) * L_SEQ + l) * 64) + q4 * 2;
  float2 a0 = __half22float2(r0[0]), a1 = __half22float2(r0[1]);
  float2 b0 = __half22float2(r1[0]), b1 = __half22float2(r1[1]);
  f16x4 res;
  res[0] = (_Float16)(w0 * a0.x + w1 * b0.x);
  res[1] = (_Float16)(w0 * a0.y + w1 * b0.y);
  res[2] = (_Float16)(w0 * a1.x + w1 * b1.x);
  res[3] = (_Float16)(w0 * a1.y + w1 * b1.y);
  int bb = n >> 4, h = n & 15;
  *(f16x4*)(attf + ((size_t)bb * L_SEQ + l) * 1024 + h * 64 + q4 * 4) = res;
}

extern "C" void kernel_launch(void* const* d_in, const int* in_sizes, int n_in,
                              void* d_out, int out_size, void* d_ws, size_t ws_size,
                              hipStream_t stream) {
  const float* x   = (const float*)d_in[0];
  const float* Wqk = (const float*)d_in[2];
  const float* Wv  = (const float*)d_in[3];
  const float* Wo  = (const float*)d_in[4];
  const float* rot = (const float*)d_in[5];
  float* out = (float*)d_out;
  char* ws = (char*)d_ws;

  float*        qk     = (float*)(ws + 0);                   // 32 MB, live until attn
  _Float16*     attf   = (_Float16*)(ws + 0);                // 16 MB, overlays qk post-attn
  _Float16*     vh     = (_Float16*)(ws + 33554432ull);      // 16 MB
  _Float16*     xhi    = (_Float16*)(ws + 50331648ull);      // 16 MB
  _Float16*     xlo    = (_Float16*)(ws + 67108864ull);      // 16 MB
  _Float16*     o      = (_Float16*)(ws + 50331648ull);      // 32 MB, overlays xhi+xlo post-gemms
  _Float16*     Wqkhi  = (_Float16*)(ws + 83886080ull);      // 2 MB
  _Float16*     Wqklo  = (_Float16*)(ws + 85983232ull);      // 2 MB
  _Float16*     WvT    = (_Float16*)(ws + 88080384ull);      // 2 MB
  _Float16*     WoT    = (_Float16*)(ws + 90177536ull);      // 2 MB
  float*        logits = (float*)(ws + 92274688ull);         // 1 MB
  unsigned int* st     = (unsigned int*)(ws + 93323264ull);  // 1 MB
  unsigned char* bucket = (unsigned char*)(ws + 94371840ull); // 256 KB

  dim3 gb(256);
  dim3 gemmGrid(8, 64);

  cvt_split<<<dim3(8192), gb, 0, stream>>>(x, xhi, xlo);
  cvt_tr_split<<<dim3(32, 32), gb, 0, stream>>>(Wqk, Wqkhi, Wqklo);
  cvt_tr_f16<<<dim3(32, 32), gb, 0, stream>>>(Wv, WvT);
  cvt_tr_f16<<<dim3(32, 32), gb, 0, stream>>>(Wo, WoT);

  gemm_f16_split<<<gemmGrid, gb, 0, stream>>>(xhi, xlo, Wqkhi, Wqklo, qk, 8192, 1024, 1024);
  gemm_f16<1><<<gemmGrid, gb, 0, stream>>>(xhi, WvT, (float*)vh, 8192, 1024, 1024);

  lsh_hash<<<dim3(16, 32), gb, 0, stream>>>(qk, rot, bucket);
  lsh_sort<<<dim3(64), gb, 0, stream>>>(bucket, st);
  lsh_attn_mfma<<<dim3(128, 32), gb, 0, stream>>>(qk, vh, st, o, logits);
  lsh_combine<<<dim3(8192), gb, 0, stream>>>((const __half*)o, logits, attf);

  gemm_f16<0><<<gemmGrid, gb, 0, stream>>>(attf, WoT, out, 8192, 1024, 1024);
}

// Round 7
// 284.382 us; speedup vs baseline: 1.0732x; 1.0732x over previous
//
#include <hip/hip_runtime.h>
#include <hip/hip_fp16.h>

#define L_SEQ 4096
#define SBK 32

typedef _Float16 f16x8 __attribute__((ext_vector_type(8)));
typedef _Float16 f16x4 __attribute__((ext_vector_type(4)));
typedef float f32x4 __attribute__((ext_vector_type(4)));

typedef __attribute__((address_space(3))) void lds_void;
typedef __attribute__((address_space(1))) void glob_void;
__device__ __forceinline__ void gload16(const _Float16* g, _Float16* l) {
  __builtin_amdgcn_global_load_lds((const glob_void*)g, (lds_void*)l, 16, 0, 0);
}

// ---------------- converts ----------------
__global__ __launch_bounds__(256)
void cvt_split(const float* __restrict__ in, _Float16* __restrict__ hi,
               _Float16* __restrict__ lo) {
  int i = blockIdx.x * 256 + threadIdx.x;
  float4 v = ((const float4*)in)[i];
  f16x4 h, l;
  h[0] = (_Float16)v.x; h[1] = (_Float16)v.y;
  h[2] = (_Float16)v.z; h[3] = (_Float16)v.w;
  l[0] = (_Float16)((v.x - (float)h[0]) * 2048.0f);
  l[1] = (_Float16)((v.y - (float)h[1]) * 2048.0f);
  l[2] = (_Float16)((v.z - (float)h[2]) * 2048.0f);
  l[3] = (_Float16)((v.w - (float)h[3]) * 2048.0f);
  *(f16x4*)(hi + (size_t)i * 4) = h;
  *(f16x4*)(lo + (size_t)i * 4) = l;
}

__global__ __launch_bounds__(256)
void cvt_tr_split(const float* __restrict__ W, _Float16* __restrict__ WTh,
                  _Float16* __restrict__ WTl) {
  __shared__ _Float16 th[32][33];
  __shared__ _Float16 tl[32][33];
  const int bx = blockIdx.x * 32, by = blockIdx.y * 32;
  const int tx = threadIdx.x & 31, ty = threadIdx.x >> 5;
  #pragma unroll
  for (int i = ty; i < 32; i += 8) {
    float w = W[(size_t)(by + i) * 1024 + bx + tx];
    _Float16 h = (_Float16)w;
    th[i][tx] = h;
    tl[i][tx] = (_Float16)((w - (float)h) * 2048.0f);
  }
  __syncthreads();
  #pragma unroll
  for (int i = ty; i < 32; i += 8) {
    WTh[(size_t)(bx + i) * 1024 + by + tx] = th[tx][i];
    WTl[(size_t)(bx + i) * 1024 + by + tx] = tl[tx][i];
  }
}

__global__ __launch_bounds__(256)
void cvt_tr_f16(const float* __restrict__ W, _Float16* __restrict__ WT) {
  __shared__ _Float16 tile[32][33];
  const int bx = blockIdx.x * 32, by = blockIdx.y * 32;
  const int tx = threadIdx.x & 31, ty = threadIdx.x >> 5;
  #pragma unroll
  for (int i = ty; i < 32; i += 8)
    tile[i][tx] = (_Float16)W[(size_t)(by + i) * 1024 + bx + tx];
  __syncthreads();
  #pragma unroll
  for (int i = ty; i < 32; i += 8)
    WT[(size_t)(bx + i) * 1024 + by + tx] = tile[tx][i];
}

// ---------------- split-f16 MFMA GEMM, dbuf + counted vmcnt (hash path) -------
// C[M,Nn] = (Ahi+Alo/2048)[M,K] * (Bhi+Blo/2048)^T[Nn,K], scatter f32 [n][l][d]
// BK=32, buffers [2][128][32] x 4 streams = 64 KB LDS.
__global__ __launch_bounds__(256)
void gemm_f16_split(const _Float16* __restrict__ Ahi, const _Float16* __restrict__ Alo,
                    const _Float16* __restrict__ Bhi, const _Float16* __restrict__ Blo,
                    float* __restrict__ C, int M, int K, int Nn) {
  __shared__ _Float16 Ash[2][128 * SBK];
  __shared__ _Float16 Asl[2][128 * SBK];
  __shared__ _Float16 Bsh[2][128 * SBK];
  __shared__ _Float16 Bsl[2][128 * SBK];
  const int tid = threadIdx.x;
  const int lane = tid & 63, wid = tid >> 6;
  const int wr = wid >> 1, wc = wid & 1;
  // XCD-aware remap: XCD k (= f%8) owns row-blocks [8k, 8k+8), all col-blocks
  const int f = blockIdx.x;
  const int u = (f & 7) * 64 + (f >> 3);
  const int row0 = (u >> 3) * 128, col0 = (u & 7) * 128;

  f32x4 acch[4][4], accl[4][4];
  #pragma unroll
  for (int i = 0; i < 4; ++i)
    #pragma unroll
    for (int j = 0; j < 4; ++j) {
      acch[i][j] = (f32x4){0.f, 0.f, 0.f, 0.f};
      accl[i][j] = (f32x4){0.f, 0.f, 0.f, 0.f};
    }

  // staging: wave stages rows [wid*32, wid*32+32), 2 issues of 16 rows per stream.
  const int srcRow = lane >> 2;
  const int srcColH = ((lane & 3) ^ ((lane >> 3) & 3)) * 8;   // source pre-swizzle
  const size_t aoff = (size_t)(row0 + wid * 32 + srcRow) * K + srcColH;
  const size_t boff = (size_t)(col0 + wid * 32 + srcRow) * K + srcColH;
  const int ld0 = (wid * 32) * SBK;
  const int ld1 = (wid * 32 + 16) * SBK;

  const int fr = lane & 15, g = lane >> 4;
  const int koH = (g ^ ((fr >> 1) & 3)) * 8;   // read swizzle (same involution)

#define STAGE_SPLIT(buf, k0) do {                                        \
    gload16(Ahi + aoff + (k0), &Ash[buf][ld0]);                          \
    gload16(Ahi + aoff + 16 * (size_t)K + (k0), &Ash[buf][ld1]);         \
    gload16(Alo + aoff + (k0), &Asl[buf][ld0]);                          \
    gload16(Alo + aoff + 16 * (size_t)K + (k0), &Asl[buf][ld1]);         \
    gload16(Bhi + boff + (k0), &Bsh[buf][ld0]);                          \
    gload16(Bhi + boff + 16 * (size_t)K + (k0), &Bsh[buf][ld1]);         \
    gload16(Blo + boff + (k0), &Bsl[buf][ld0]);                          \
    gload16(Blo + boff + 16 * (size_t)K + (k0), &Bsl[buf][ld1]);         \
  } while (0)

  STAGE_SPLIT(0, 0);

  const int NT = K / SBK;   // 32
  for (int t = 0; t < NT; ++t) {
    const int cur = t & 1, nxt = cur ^ 1;
    if (t + 1 < NT) {
      STAGE_SPLIT(nxt, (size_t)(t + 1) * SBK);
      asm volatile("s_waitcnt vmcnt(8)" ::: "memory");   // tile t landed; t+1 in flight
    } else {
      asm volatile("s_waitcnt vmcnt(0)" ::: "memory");
    }
    __builtin_amdgcn_s_barrier();
    __builtin_amdgcn_sched_barrier(0);

    f16x8 ah[4], al[4], bh[4], bl[4];
    #pragma unroll
    for (int fi = 0; fi < 4; ++fi) {
      ah[fi] = *(const f16x8*)&Ash[cur][(wr * 64 + fi * 16 + fr) * SBK + koH];
      al[fi] = *(const f16x8*)&Asl[cur][(wr * 64 + fi * 16 + fr) * SBK + koH];
    }
    #pragma unroll
    for (int fj = 0; fj < 4; ++fj) {
      bh[fj] = *(const f16x8*)&Bsh[cur][(wc * 64 + fj * 16 + fr) * SBK + koH];
      bl[fj] = *(const f16x8*)&Bsl[cur][(wc * 64 + fj * 16 + fr) * SBK + koH];
    }
    #pragma unroll
    for (int fi = 0; fi < 4; ++fi)
      #pragma unroll
      for (int fj = 0; fj < 4; ++fj) {
        acch[fi][fj] = __builtin_amdgcn_mfma_f32_16x16x32_f16(
            ah[fi], bh[fj], acch[fi][fj], 0, 0, 0);
        accl[fi][fj] = __builtin_amdgcn_mfma_f32_16x16x32_f16(
            al[fi], bh[fj], accl[fi][fj], 0, 0, 0);
        accl[fi][fj] = __builtin_amdgcn_mfma_f32_16x16x32_f16(
            ah[fi], bl[fj], accl[fi][fj], 0, 0, 0);
      }
    __builtin_amdgcn_s_barrier();     // all waves done reading buf cur
    __builtin_amdgcn_sched_barrier(0);
  }
#undef STAGE_SPLIT

  #pragma unroll
  for (int fi = 0; fi < 4; ++fi) {
    #pragma unroll
    for (int fj = 0; fj < 4; ++fj) {
      const int col = col0 + wc * 64 + fj * 16 + fr;
      #pragma unroll
      for (int r = 0; r < 4; ++r) {
        const int row = row0 + wr * 64 + fi * 16 + g * 4 + r;
        int b = row >> 12, l = row & 4095;
        int h = col >> 6, d = col & 63;
        C[(((size_t)(b * 16 + h) * L_SEQ) + l) * 64 + d] =
            acch[fi][fj][r] + accl[fi][fj][r] * (1.0f / 2048.0f);
      }
    }
  }
}

// ---------------- f16 MFMA GEMM, dbuf + counted vmcnt: C = A * BT^T ----------------
// MODE 0: C row-major f32; MODE 1: scatter f16 to [n][l][d]
template<int MODE>
__global__ __launch_bounds__(256)
void gemm_f16(const _Float16* __restrict__ A, const _Float16* __restrict__ BT,
              float* __restrict__ C, int M, int K, int Nn) {
  __shared__ _Float16 As[2][128 * 64];
  __shared__ _Float16 Bs[2][128 * 64];
  const int tid = threadIdx.x;
  const int lane = tid & 63, wid = tid >> 6;
  const int wr = wid >> 1, wc = wid & 1;
  const int f = blockIdx.x;
  const int u = (f & 7) * 64 + (f >> 3);
  const int row0 = (u >> 3) * 128, col0 = (u & 7) * 128;

  f32x4 acc[4][4];
  #pragma unroll
  for (int i = 0; i < 4; ++i)
    #pragma unroll
    for (int j = 0; j < 4; ++j)
      acc[i][j] = (f32x4){0.f, 0.f, 0.f, 0.f};

  const int srow = (lane >> 3);
  const int scol = ((lane & 7) ^ srow) * 8;
  const _Float16* ga = A + (size_t)(row0 + wid * 32 + srow) * K + scol;
  const _Float16* gb = BT + (size_t)(col0 + wid * 32 + srow) * K + scol;
  const int lbase = (wid * 32) * 64;
  const int fr = lane & 15, g = lane >> 4;

#define STAGE_F16(buf, k0) do {                                          \
    _Pragma("unroll")                                                    \
    for (int i_ = 0; i_ < 4; ++i_) {                                     \
      gload16(ga + (k0) + (size_t)i_ * 8 * K, &As[buf][lbase + i_ * 8 * 64]); \
      gload16(gb + (k0) + (size_t)i_ * 8 * K, &Bs[buf][lbase + i_ * 8 * 64]); \
    }                                                                    \
  } while (0)

  STAGE_F16(0, 0);

  const int NT = K / 64;   // 16
  for (int t = 0; t < NT; ++t) {
    const int cur = t & 1, nxt = cur ^ 1;
    if (t + 1 < NT) {
      STAGE_F16(nxt, (size_t)(t + 1) * 64);
      asm volatile("s_waitcnt vmcnt(8)" ::: "memory");
    } else {
      asm volatile("s_waitcnt vmcnt(0)" ::: "memory");
    }
    __builtin_amdgcn_s_barrier();
    __builtin_amdgcn_sched_barrier(0);

    f16x8 af[4][2], bf[4][2];
    #pragma unroll
    for (int fi = 0; fi < 4; ++fi) {
      const int ra = (wr * 64 + fi * 16 + fr) * 64;
      const int rb = (wc * 64 + fi * 16 + fr) * 64;
      #pragma unroll
      for (int ks = 0; ks < 2; ++ks) {
        const int ko = (ks * 32 + g * 8) ^ ((fr & 7) * 8);
        af[fi][ks] = *(const f16x8*)(&As[cur][ra + ko]);
        bf[fi][ks] = *(const f16x8*)(&Bs[cur][rb + ko]);
      }
    }
    #pragma unroll
    for (int ks = 0; ks < 2; ++ks)
      #pragma unroll
      for (int fi = 0; fi < 4; ++fi)
        #pragma unroll
        for (int fj = 0; fj < 4; ++fj)
          acc[fi][fj] = __builtin_amdgcn_mfma_f32_16x16x32_f16(
              af[fi][ks], bf[fj][ks], acc[fi][fj], 0, 0, 0);
    __builtin_amdgcn_s_barrier();
    __builtin_amdgcn_sched_barrier(0);
  }
#undef STAGE_F16

  _Float16* Ch = (_Float16*)C;
  #pragma unroll
  for (int fi = 0; fi < 4; ++fi) {
    #pragma unroll
    for (int fj = 0; fj < 4; ++fj) {
      const int col = col0 + wc * 64 + fj * 16 + fr;
      #pragma unroll
      for (int r = 0; r < 4; ++r) {
        const int row = row0 + wr * 64 + fi * 16 + g * 4 + r;
        if (MODE == 0) {
          C[(size_t)row * Nn + col] = acc[fi][fj][r];
        } else {
          int b = row >> 12, l = row & 4095;
          int h = col >> 6, d = col & 63;
          Ch[(((size_t)(b * 16 + h) * L_SEQ) + l) * 64 + d] = (_Float16)acc[fi][fj][r];
        }
      }
    }
  }
}

// ---------------- LSH hashing (fp32 exact) ----------------
__global__ __launch_bounds__(256)
void lsh_hash(const float* __restrict__ qk, const float* __restrict__ rot,
              unsigned char* __restrict__ bucket) {
  __shared__ float rots[4096];
  const int tid = threadIdx.x;
  for (int idx = tid; idx < 4096; idx += 256) rots[idx] = rot[idx];
  __syncthreads();
  const int n = blockIdx.y;
  const int l = blockIdx.x * 256 + tid;
  const float4* q4p = (const float4*)(qk + ((size_t)n * L_SEQ + l) * 64);
  float qr[64];
  #pragma unroll
  for (int t4 = 0; t4 < 16; ++t4) {
    float4 t = q4p[t4];
    qr[t4 * 4 + 0] = t.x; qr[t4 * 4 + 1] = t.y;
    qr[t4 * 4 + 2] = t.z; qr[t4 * 4 + 3] = t.w;
  }
  #pragma unroll 1
  for (int hr = 0; hr < 2; ++hr) {
    float val[32];
    #pragma unroll
    for (int rb = 0; rb < 32; ++rb) val[rb] = 0.f;
    #pragma unroll
    for (int d = 0; d < 64; ++d) {
      float qd = qr[d];
      const float* rp = &rots[d * 64 + hr * 32];
      #pragma unroll
      for (int rb = 0; rb < 32; ++rb) val[rb] += qd * rp[rb];
    }
    float best = val[0]; int bidx = 0;
    #pragma unroll
    for (int k = 1; k < 32; ++k) { if (val[k] > best) { best = val[k]; bidx = k; } }
    #pragma unroll
    for (int k = 0; k < 32; ++k) { float vn = -val[k]; if (vn > best) { best = vn; bidx = 32 + k; } }
    bucket[((size_t)n * 2 + hr) * L_SEQ + l] = (unsigned char)bidx;
  }
}

// ---------------- parallel stable counting sort per (n, round) ----------------
__global__ __launch_bounds__(256)
void lsh_sort(const unsigned char* __restrict__ bucket, unsigned int* __restrict__ st) {
  __shared__ unsigned short cnt[64][257];
  __shared__ unsigned int bstart[64];
  __shared__ unsigned char bkt[4096];
  const int nr = blockIdx.x;
  const int tid = threadIdx.x;
  const unsigned char* bsrc = bucket + (size_t)nr * L_SEQ;
  for (int i = tid; i < 1024; i += 256)
    ((unsigned int*)bkt)[i] = ((const unsigned int*)bsrc)[i];
  #pragma unroll
  for (int b = 0; b < 64; ++b) cnt[b][tid] = 0;
  __syncthreads();
  uint4 wv = ((const uint4*)bkt)[tid];
  unsigned int wsg[4] = {wv.x, wv.y, wv.z, wv.w};
  #pragma unroll
  for (int k = 0; k < 16; ++k) {
    int b = (wsg[k >> 2] >> ((k & 3) * 8)) & 63;
    cnt[b][tid]++;
  }
  __syncthreads();
  if (tid < 64) {
    const int b = tid;
    unsigned int run = 0;
    for (int t = 0; t < 256; ++t) {
      unsigned int c = cnt[b][t];
      cnt[b][t] = (unsigned short)run;
      run += c;
    }
    unsigned int incl = run;
    #pragma unroll
    for (int off = 1; off < 64; off <<= 1) {
      unsigned int up = (unsigned int)__shfl_up((int)incl, off);
      if (tid >= off) incl += up;
    }
    bstart[b] = incl - run;
  }
  __syncthreads();
  const int n = nr >> 1, r = nr & 1;
  unsigned int* dst = st + (size_t)n * 8192 + (size_t)r * 4096;
  #pragma unroll
  for (int k = 0; k < 16; ++k) {
    int b = (wsg[k >> 2] >> ((k & 3) * 8)) & 63;
    unsigned int idx = bstart[b] + cnt[b][tid];
    cnt[b][tid]++;
    dst[idx] = (unsigned int)(tid * 16 + k);
  }
}

// ---------------- MFMA chunked local attention ----------------
__global__ __launch_bounds__(256)
void lsh_attn_mfma(const float* __restrict__ qkf, const _Float16* __restrict__ vh,
                   const unsigned int* __restrict__ st,
                   _Float16* __restrict__ o, float* __restrict__ logits) {
  __shared__ _Float16 Kl[128 * 64];
  __shared__ _Float16 Vt[64 * 128];
  __shared__ _Float16 Pl[64 * 128];
  __shared__ float rsqs[128];
  __shared__ float partial[256];
  __shared__ int posl[128];

  const int tid = threadIdx.x;
  const int lane = tid & 63, wid = tid >> 6;
  const int fr = lane & 15, g = lane >> 4;
  const int c = blockIdx.x, n = blockIdx.y;
  const int cprev = (c + 127) & 127;

  if (tid < 128) {
    int p = (tid < 64) ? (c * 64 + tid) : (cprev * 64 + (tid - 64));
    posl[tid] = (int)st[(size_t)n * 8192 + p];
  }
  __syncthreads();

  {
    const int j = tid >> 1, h = tid & 1;
    const int gpos = posl[j];
    const float4* srcK = (const float4*)(qkf + ((size_t)n * L_SEQ + gpos) * 64 + h * 32);
    const f16x8* srcV = (const f16x8*)(vh + ((size_t)n * L_SEQ + gpos) * 64 + h * 32);
    float ss = 0.f;
    #pragma unroll
    for (int i = 0; i < 4; ++i) {
      float4 f0 = srcK[2 * i], f1 = srcK[2 * i + 1];
      ss += f0.x * f0.x + f0.y * f0.y + f0.z * f0.z + f0.w * f0.w;
      ss += f1.x * f1.x + f1.y * f1.y + f1.z * f1.z + f1.w * f1.w;
      f16x8 kv;
      kv[0] = (_Float16)f0.x; kv[1] = (_Float16)f0.y;
      kv[2] = (_Float16)f0.z; kv[3] = (_Float16)f0.w;
      kv[4] = (_Float16)f1.x; kv[5] = (_Float16)f1.y;
      kv[6] = (_Float16)f1.z; kv[7] = (_Float16)f1.w;
      int ch = h * 4 + i;
      *(f16x8*)(&Kl[j * 64 + ((ch ^ (j & 7)) * 8)]) = kv;
      f16x8 vv4 = srcV[i];
      #pragma unroll
      for (int e = 0; e < 8; ++e) {
        int d = h * 32 + i * 8 + e;
        Vt[d * 128 + (j ^ ((d & 7) << 3))] = vv4[e];
      }
    }
    partial[tid] = ss;
  }
  __syncthreads();
  if (tid < 128)
    rsqs[tid] = rsqrtf(fmaxf(partial[tid * 2] + partial[tid * 2 + 1], 1e-12f));
  __syncthreads();

  const int q0 = wid * 16;
  f32x4 acc[8];
  #pragma unroll
  for (int t = 0; t < 8; ++t) acc[t] = (f32x4){0.f, 0.f, 0.f, 0.f};
  f16x8 aq[2];
  #pragma unroll
  for (int ks = 0; ks < 2; ++ks)
    aq[ks] = *(const f16x8*)&Kl[(q0 + fr) * 64 + (((ks * 4 + g) ^ (fr & 7)) * 8)];
  #pragma unroll
  for (int t = 0; t < 8; ++t) {
    #pragma unroll
    for (int ks = 0; ks < 2; ++ks) {
      f16x8 bk = *(const f16x8*)&Kl[(t * 16 + fr) * 64 + (((ks * 4 + g) ^ (fr & 7)) * 8)];
      acc[t] = __builtin_amdgcn_mfma_f32_16x16x32_f16(aq[ks], bk, acc[t], 0, 0, 0);
    }
  }

  float sc[8][4];
  int pq[4];
  #pragma unroll
  for (int r = 0; r < 4; ++r) pq[r] = posl[q0 + g * 4 + r];
  #pragma unroll
  for (int t = 0; t < 8; ++t) {
    float rs = rsqs[t * 16 + fr] * 0.125f;
    int pk = posl[t * 16 + fr];
    #pragma unroll
    for (int r = 0; r < 4; ++r) {
      float v_ = acc[t][r] * rs;
      if (pq[r] == pk) v_ += -1e5f;
      sc[t][r] = v_;
    }
  }
  float lsef[4];
  #pragma unroll
  for (int r = 0; r < 4; ++r) {
    float m = sc[0][r];
    #pragma unroll
    for (int t = 1; t < 8; ++t) m = fmaxf(m, sc[t][r]);
    #pragma unroll
    for (int off = 1; off < 16; off <<= 1) m = fmaxf(m, __shfl_xor(m, off, 64));
    float s = 0.f;
    #pragma unroll
    for (int t = 0; t < 8; ++t) { float e = __expf(sc[t][r] - m); sc[t][r] = e; s += e; }
    #pragma unroll
    for (int off = 1; off < 16; off <<= 1) s += __shfl_xor(s, off, 64);
    lsef[r] = m + __logf(s);
    float f = 1.0f / s;
    #pragma unroll
    for (int t = 0; t < 8; ++t) sc[t][r] *= f;
  }

  #pragma unroll
  for (int t = 0; t < 8; ++t)
    #pragma unroll
    for (int r = 0; r < 4; ++r) {
      int q = q0 + g * 4 + r;
      Pl[q * 128 + ((t * 16 + fr) ^ ((q & 7) << 3))] = (_Float16)sc[t][r];
    }
  const int rr = c >> 6;
  if (fr == 0) {
    #pragma unroll
    for (int r = 0; r < 4; ++r) {
      int q = q0 + g * 4 + r;
      logits[((size_t)n * 2 + rr) * L_SEQ + posl[q]] = lsef[r];
    }
  }

  f32x4 acc2[4];
  #pragma unroll
  for (int td = 0; td < 4; ++td) acc2[td] = (f32x4){0.f, 0.f, 0.f, 0.f};
  #pragma unroll
  for (int s = 0; s < 4; ++s) {
    f16x8 ap = *(const f16x8*)&Pl[(q0 + fr) * 128 + (((s * 4 + g) ^ (fr & 7)) * 8)];
    #pragma unroll
    for (int td = 0; td < 4; ++td) {
      f16x8 bv = *(const f16x8*)&Vt[(td * 16 + fr) * 128 + (((s * 4 + g) ^ (fr & 7)) * 8)];
      acc2[td] = __builtin_amdgcn_mfma_f32_16x16x32_f16(ap, bv, acc2[td], 0, 0, 0);
    }
  }
  #pragma unroll
  for (int r = 0; r < 4; ++r) {
    int q = q0 + g * 4 + r;
    size_t base = (((size_t)n * 2 + rr) * L_SEQ + posl[q]) * 64;
    #pragma unroll
    for (int td = 0; td < 4; ++td)
      o[base + td * 16 + fr] = (_Float16)acc2[td][r];
  }
}

// ---------------- combine hash rounds -> f16 att [8192][1024] ----------------
__global__ __launch_bounds__(256)
void lsh_combine(const __half* __restrict__ o, const float* __restrict__ logits,
                 _Float16* __restrict__ attf) {
  size_t gid = (size_t)blockIdx.x * 256 + threadIdx.x;
  int q4 = (int)(gid & 15);
  size_t nl = gid >> 4;
  int n = (int)(nl >> 12), l = (int)(nl & 4095);
  float l0 = logits[((size_t)n * 2 + 0) * L_SEQ + l];
  float l1 = logits[((size_t)n * 2 + 1) * L_SEQ + l];
  float m = fmaxf(l0, l1);
  float e0 = __expf(l0 - m), e1 = __expf(l1 - m);
  float inv = 1.0f / (e0 + e1);
  float w0 = e0 * inv, w1 = e1 * inv;
  const __half2* r0 = (const __half2*)(o + (((size_t)n * 2 + 0) * L_SEQ + l) * 64) + q4 * 2;
  const __half2* r1 = (const __half2*)(o + (((size_t)n * 2 + 1) * L_SEQ + l) * 64) + q4 * 2;
  float2 a0 = __half22float2(r0[0]), a1 = __half22float2(r0[1]);
  float2 b0 = __half22float2(r1[0]), b1 = __half22float2(r1[1]);
  f16x4 res;
  res[0] = (_Float16)(w0 * a0.x + w1 * b0.x);
  res[1] = (_Float16)(w0 * a0.y + w1 * b0.y);
  res[2] = (_Float16)(w0 * a1.x + w1 * b1.x);
  res[3] = (_Float16)(w0 * a1.y + w1 * b1.y);
  int bb = n >> 4, h = n & 15;
  *(f16x4*)(attf + ((size_t)bb * L_SEQ + l) * 1024 + h * 64 + q4 * 4) = res;
}

extern "C" void kernel_launch(void* const* d_in, const int* in_sizes, int n_in,
                              void* d_out, int out_size, void* d_ws, size_t ws_size,
                              hipStream_t stream) {
  const float* x   = (const float*)d_in[0];
  const float* Wqk = (const float*)d_in[2];
  const float* Wv  = (const float*)d_in[3];
  const float* Wo  = (const float*)d_in[4];
  const float* rot = (const float*)d_in[5];
  float* out = (float*)d_out;
  char* ws = (char*)d_ws;

  float*        qk     = (float*)(ws + 0);                   // 32 MB, live until attn
  _Float16*     attf   = (_Float16*)(ws + 0);                // 16 MB, overlays qk post-attn
  _Float16*     vh     = (_Float16*)(ws + 33554432ull);      // 16 MB
  _Float16*     xhi    = (_Float16*)(ws + 50331648ull);      // 16 MB
  _Float16*     xlo    = (_Float16*)(ws + 67108864ull);      // 16 MB
  _Float16*     o      = (_Float16*)(ws + 50331648ull);      // 32 MB, overlays xhi+xlo post-gemms
  _Float16*     Wqkhi  = (_Float16*)(ws + 83886080ull);      // 2 MB
  _Float16*     Wqklo  = (_Float16*)(ws + 85983232ull);      // 2 MB
  _Float16*     WvT    = (_Float16*)(ws + 88080384ull);      // 2 MB
  _Float16*     WoT    = (_Float16*)(ws + 90177536ull);      // 2 MB
  float*        logits = (float*)(ws + 92274688ull);         // 1 MB
  unsigned int* st     = (unsigned int*)(ws + 93323264ull);  // 1 MB
  unsigned char* bucket = (unsigned char*)(ws + 94371840ull); // 256 KB

  dim3 gb(256);
  dim3 gemmGrid(512);

  cvt_split<<<dim3(8192), gb, 0, stream>>>(x, xhi, xlo);
  cvt_tr_split<<<dim3(32, 32), gb, 0, stream>>>(Wqk, Wqkhi, Wqklo);
  cvt_tr_f16<<<dim3(32, 32), gb, 0, stream>>>(Wv, WvT);
  cvt_tr_f16<<<dim3(32, 32), gb, 0, stream>>>(Wo, WoT);

  gemm_f16_split<<<gemmGrid, gb, 0, stream>>>(xhi, xlo, Wqkhi, Wqklo, qk, 8192, 1024, 1024);
  gemm_f16<1><<<gemmGrid, gb, 0, stream>>>(xhi, WvT, (float*)vh, 8192, 1024, 1024);

  lsh_hash<<<dim3(16, 32), gb, 0, stream>>>(qk, rot, bucket);
  lsh_sort<<<dim3(64), gb, 0, stream>>>(bucket, st);
  lsh_attn_mfma<<<dim3(128, 32), gb, 0, stream>>>(qk, vh, st, o, logits);
  lsh_combine<<<dim3(8192), gb, 0, stream>>>((const __half*)o, logits, attf);

  gemm_f16<0><<<gemmGrid, gb, 0, stream>>>(attf, WoT, out, 8192, 1024, 1024);
}

// Round 8
// 265.755 us; speedup vs baseline: 1.1484x; 1.0701x over previous
//
#include <hip/hip_runtime.h>
#include <hip/hip_fp16.h>

#define L_SEQ 4096
#define THR_GAP 0.08f
#define FIX_CAP 8192

typedef _Float16 f16x8 __attribute__((ext_vector_type(8)));
typedef _Float16 f16x4 __attribute__((ext_vector_type(4)));
typedef float f32x4 __attribute__((ext_vector_type(4)));

typedef __attribute__((address_space(3))) void lds_void;
typedef __attribute__((address_space(1))) void glob_void;
__device__ __forceinline__ void gload16(const _Float16* g, _Float16* l) {
  __builtin_amdgcn_global_load_lds((const glob_void*)g, (lds_void*)l, 16, 0, 0);
}

// ---------------- converts ----------------
__global__ __launch_bounds__(256)
void cvt_f16(const float* __restrict__ in, _Float16* __restrict__ out_) {
  int i = blockIdx.x * 256 + threadIdx.x;
  float4 v = ((const float4*)in)[i];
  f16x4 h;
  h[0] = (_Float16)v.x; h[1] = (_Float16)v.y;
  h[2] = (_Float16)v.z; h[3] = (_Float16)v.w;
  *(f16x4*)(out_ + (size_t)i * 4) = h;
}

__global__ __launch_bounds__(256)
void cvt_tr_f16(const float* __restrict__ W, _Float16* __restrict__ WT) {
  __shared__ _Float16 tile[32][33];
  const int bx = blockIdx.x * 32, by = blockIdx.y * 32;
  const int tx = threadIdx.x & 31, ty = threadIdx.x >> 5;
  #pragma unroll
  for (int i = ty; i < 32; i += 8)
    tile[i][tx] = (_Float16)W[(size_t)(by + i) * 1024 + bx + tx];
  __syncthreads();
  #pragma unroll
  for (int i = ty; i < 32; i += 8)
    WT[(size_t)(bx + i) * 1024 + by + tx] = tile[tx][i];
}

// WR[g=h*2+nh][e][r] = sum_d Wqk[e][h][d] * rot[d][nh][r]  (fp32)
__global__ __launch_bounds__(256)
void wr_precompute(const float* __restrict__ Wqk, const float* __restrict__ rot,
                   float* __restrict__ WR) {
  __shared__ float rs[64][32];
  const int g = blockIdx.x;
  const int h = g >> 1, nh = g & 1;
  const int tid = threadIdx.x;
  for (int idx = tid; idx < 2048; idx += 256) {
    int d = idx >> 5, r = idx & 31;
    rs[d][r] = rot[(d * 2 + nh) * 32 + r];
  }
  __syncthreads();
  const int e = blockIdx.y * 128 + (tid >> 1);
  const int r0 = (tid & 1) * 16;
  const float* wp = Wqk + (size_t)e * 1024 + h * 64;
  float w[64];
  #pragma unroll
  for (int d = 0; d < 64; ++d) w[d] = wp[d];
  float acc[16];
  #pragma unroll
  for (int r = 0; r < 16; ++r) acc[r] = 0.f;
  for (int d = 0; d < 64; ++d) {
    float wd = w[d];
    #pragma unroll
    for (int r = 0; r < 16; ++r) acc[r] += wd * rs[d][r0 + r];
  }
  float* dst = WR + ((size_t)g * 1024 + e) * 32 + r0;
  #pragma unroll
  for (int r = 0; r < 16; ++r) dst[r] = acc[r];
}

// ---------------- f16 MFMA GEMM, dbuf + counted vmcnt: C = A * BT^T ----------------
// MODE 0: C row-major f32; MODE 1: scatter f16 to [n][l][d]
template<int MODE>
__global__ __launch_bounds__(256)
void gemm_f16(const _Float16* __restrict__ A, const _Float16* __restrict__ BT,
              float* __restrict__ C, int M, int K, int Nn) {
  __shared__ _Float16 As[2][128 * 64];
  __shared__ _Float16 Bs[2][128 * 64];
  const int tid = threadIdx.x;
  const int lane = tid & 63, wid = tid >> 6;
  const int wr = wid >> 1, wc = wid & 1;
  const int f = blockIdx.x;
  const int u = (f & 7) * 64 + (f >> 3);
  const int row0 = (u >> 3) * 128, col0 = (u & 7) * 128;

  f32x4 acc[4][4];
  #pragma unroll
  for (int i = 0; i < 4; ++i)
    #pragma unroll
    for (int j = 0; j < 4; ++j)
      acc[i][j] = (f32x4){0.f, 0.f, 0.f, 0.f};

  const int srow = (lane >> 3);
  const int scol = ((lane & 7) ^ srow) * 8;
  const _Float16* ga = A + (size_t)(row0 + wid * 32 + srow) * K + scol;
  const _Float16* gb = BT + (size_t)(col0 + wid * 32 + srow) * K + scol;
  const int lbase = (wid * 32) * 64;
  const int fr = lane & 15, g = lane >> 4;

#define STAGE_F16(buf, k0) do {                                          \
    _Pragma("unroll")                                                    \
    for (int i_ = 0; i_ < 4; ++i_) {                                     \
      gload16(ga + (k0) + (size_t)i_ * 8 * K, &As[buf][lbase + i_ * 8 * 64]); \
      gload16(gb + (k0) + (size_t)i_ * 8 * K, &Bs[buf][lbase + i_ * 8 * 64]); \
    }                                                                    \
  } while (0)

  STAGE_F16(0, 0);

  const int NT = K / 64;
  for (int t = 0; t < NT; ++t) {
    const int cur = t & 1, nxt = cur ^ 1;
    if (t + 1 < NT) {
      STAGE_F16(nxt, (size_t)(t + 1) * 64);
      asm volatile("s_waitcnt vmcnt(8)" ::: "memory");
    } else {
      asm volatile("s_waitcnt vmcnt(0)" ::: "memory");
    }
    __builtin_amdgcn_s_barrier();
    __builtin_amdgcn_sched_barrier(0);

    f16x8 af[4][2], bf[4][2];
    #pragma unroll
    for (int fi = 0; fi < 4; ++fi) {
      const int ra = (wr * 64 + fi * 16 + fr) * 64;
      const int rb = (wc * 64 + fi * 16 + fr) * 64;
      #pragma unroll
      for (int ks = 0; ks < 2; ++ks) {
        const int ko = (ks * 32 + g * 8) ^ ((fr & 7) * 8);
        af[fi][ks] = *(const f16x8*)(&As[cur][ra + ko]);
        bf[fi][ks] = *(const f16x8*)(&Bs[cur][rb + ko]);
      }
    }
    #pragma unroll
    for (int ks = 0; ks < 2; ++ks)
      #pragma unroll
      for (int fi = 0; fi < 4; ++fi)
        #pragma unroll
        for (int fj = 0; fj < 4; ++fj)
          acc[fi][fj] = __builtin_amdgcn_mfma_f32_16x16x32_f16(
              af[fi][ks], bf[fj][ks], acc[fi][fj], 0, 0, 0);
    __builtin_amdgcn_s_barrier();
    __builtin_amdgcn_sched_barrier(0);
  }
#undef STAGE_F16

  _Float16* Ch = (_Float16*)C;
  #pragma unroll
  for (int fi = 0; fi < 4; ++fi) {
    #pragma unroll
    for (int fj = 0; fj < 4; ++fj) {
      const int col = col0 + wc * 64 + fj * 16 + fr;
      #pragma unroll
      for (int r = 0; r < 4; ++r) {
        const int row = row0 + wr * 64 + fi * 16 + g * 4 + r;
        if (MODE == 0) {
          C[(size_t)row * Nn + col] = acc[fi][fj][r];
        } else {
          int b = row >> 12, l = row & 4095;
          int h = col >> 6, d = col & 63;
          Ch[(((size_t)(b * 16 + h) * L_SEQ) + l) * 64 + d] = (_Float16)acc[fi][fj][r];
        }
      }
    }
  }
}

// ---------------- LSH hashing from f16 qk + ambiguity flagging ----------------
__global__ __launch_bounds__(256)
void lsh_hash2(const _Float16* __restrict__ qkh, const float* __restrict__ rot,
               unsigned char* __restrict__ bucket,
               unsigned int* __restrict__ lists, unsigned int* __restrict__ cnt) {
  __shared__ float rots[4096];
  const int tid = threadIdx.x;
  for (int idx = tid; idx < 4096; idx += 256) rots[idx] = rot[idx];
  __syncthreads();
  const int n = blockIdx.y;
  const int l = blockIdx.x * 256 + tid;
  const f16x8* qp = (const f16x8*)(qkh + ((size_t)n * L_SEQ + l) * 64);
  float qr[64];
  #pragma unroll
  for (int t8 = 0; t8 < 8; ++t8) {
    f16x8 v = qp[t8];
    #pragma unroll
    for (int e = 0; e < 8; ++e) qr[t8 * 8 + e] = (float)v[e];
  }
  #pragma unroll 1
  for (int hr = 0; hr < 2; ++hr) {
    float val[32];
    #pragma unroll
    for (int rb = 0; rb < 32; ++rb) val[rb] = 0.f;
    #pragma unroll
    for (int d = 0; d < 64; ++d) {
      float qd = qr[d];
      const float* rp = &rots[d * 64 + hr * 32];
      #pragma unroll
      for (int rb = 0; rb < 32; ++rb) val[rb] += qd * rp[rb];
    }
    float m1 = val[0]; int bi = 0;
    #pragma unroll
    for (int k = 1; k < 32; ++k) { if (val[k] > m1) { m1 = val[k]; bi = k; } }
    #pragma unroll
    for (int k = 0; k < 32; ++k) { float vn = -val[k]; if (vn > m1) { m1 = vn; bi = 32 + k; } }
    float m2 = -3.0e38f;
    #pragma unroll
    for (int k = 0; k < 32; ++k) { if (k != bi) m2 = fmaxf(m2, val[k]); }
    #pragma unroll
    for (int k = 0; k < 32; ++k) { if (32 + k != bi) m2 = fmaxf(m2, -val[k]); }
    bucket[((size_t)n * 2 + hr) * L_SEQ + l] = (unsigned char)bi;
    if (m1 - m2 < THR_GAP) {
      int g = (n & 15) * 2 + hr;
      unsigned int pos = atomicAdd(&cnt[g], 1u);
      if (pos < FIX_CAP)
        lists[(size_t)g * FIX_CAP + pos] = ((unsigned int)n << 12) | (unsigned int)l;
    }
  }
}

// ---------------- exact fp32 fixup for flagged decisions ----------------
__global__ __launch_bounds__(256)
void lsh_fixup(const float* __restrict__ x, const float* __restrict__ WR,
               const unsigned int* __restrict__ lists,
               const unsigned int* __restrict__ cnt,
               unsigned long long* __restrict__ rotbuf,
               unsigned char* __restrict__ bucket) {
  __shared__ float wr[16][1024];   // [r-in-half][e], 64 KB
  const int bid = blockIdx.x;
  const int g = bid >> 3, bg = bid & 7;
  const int nh = g & 1;
  const int tid = threadIdx.x, lane = tid & 63, wv = tid >> 6;
  const unsigned int nfix = min(cnt[g], (unsigned int)FIX_CAP);
  const unsigned int* mylist = lists + (size_t)g * FIX_CAP;

  for (int rh = 0; rh < 2; ++rh) {
    __syncthreads();
    for (int idx = tid; idx < 16384; idx += 256) {
      int e = idx >> 4, r = idx & 15;
      wr[r][e] = WR[((size_t)g * 1024 + e) * 32 + rh * 16 + r];
    }
    __syncthreads();
    for (unsigned int i0 = ((unsigned int)(bg * 4 + wv)) * 4; i0 < nfix; i0 += 128) {
      float4 xd[4][4];
      int nn[4], ll[4];
      bool va[4];
      #pragma unroll
      for (int d = 0; d < 4; ++d) {
        unsigned int i = i0 + d;
        va[d] = (i < nfix);
        unsigned int ent = mylist[va[d] ? i : i0];
        nn[d] = (int)(ent >> 12); ll[d] = (int)(ent & 4095);
        const float* xr = x + ((size_t)(nn[d] >> 4) * 4096 + ll[d]) * 1024 + lane * 4;
        #pragma unroll
        for (int k = 0; k < 4; ++k) xd[d][k] = *(const float4*)(xr + k * 256);
      }
      float acc[4][16];
      #pragma unroll
      for (int d = 0; d < 4; ++d)
        #pragma unroll
        for (int r = 0; r < 16; ++r) acc[d][r] = 0.f;
      #pragma unroll
      for (int k = 0; k < 4; ++k) {
        #pragma unroll
        for (int r = 0; r < 16; ++r) {
          float4 w4 = *(const float4*)&wr[r][lane * 4 + k * 256];
          #pragma unroll
          for (int d = 0; d < 4; ++d)
            acc[d][r] += xd[d][k].x * w4.x + xd[d][k].y * w4.y
                       + xd[d][k].z * w4.z + xd[d][k].w * w4.w;
        }
      }
      // cross-lane sum (e dimension)
      #pragma unroll
      for (int d = 0; d < 4; ++d)
        #pragma unroll
        for (int r = 0; r < 16; ++r) {
          float s = acc[d][r];
          #pragma unroll
          for (int off = 32; off; off >>= 1) s += __shfl_xor(s, off, 64);
          acc[d][r] = s;
        }
      if (lane == 0) {
        #pragma unroll
        for (int d = 0; d < 4; ++d) {
          if (!va[d]) continue;
          float bv = acc[d][0]; int bi = rh * 16;
          #pragma unroll
          for (int r = 1; r < 16; ++r) {
            if (acc[d][r] > bv) { bv = acc[d][r]; bi = rh * 16 + r; }
          }
          #pragma unroll
          for (int r = 0; r < 16; ++r) {
            float vn = -acc[d][r];
            if (vn > bv) { bv = vn; bi = 32 + rh * 16 + r; }
          }
          size_t rb = (size_t)g * FIX_CAP + (i0 + d);
          if (rh == 0) {
            rotbuf[rb] = ((unsigned long long)__float_as_uint(bv) << 32) | (unsigned int)bi;
          } else {
            unsigned long long p0 = rotbuf[rb];
            float v0 = __uint_as_float((unsigned int)(p0 >> 32));
            int i0x = (int)(p0 & 0xffffffffu);
            if (v0 > bv || (v0 == bv && i0x < bi)) { bv = v0; bi = i0x; }
            bucket[((size_t)(nn[d] * 2 + nh)) * L_SEQ + ll[d]] = (unsigned char)bi;
          }
        }
      }
    }
  }
}

// ---------------- parallel stable counting sort per (n, round) ----------------
__global__ __launch_bounds__(256)
void lsh_sort(const unsigned char* __restrict__ bucket, unsigned int* __restrict__ st) {
  __shared__ unsigned short cnt[64][257];
  __shared__ unsigned int bstart[64];
  __shared__ unsigned char bkt[4096];
  const int nr = blockIdx.x;
  const int tid = threadIdx.x;
  const unsigned char* bsrc = bucket + (size_t)nr * L_SEQ;
  for (int i = tid; i < 1024; i += 256)
    ((unsigned int*)bkt)[i] = ((const unsigned int*)bsrc)[i];
  #pragma unroll
  for (int b = 0; b < 64; ++b) cnt[b][tid] = 0;
  __syncthreads();
  uint4 wv = ((const uint4*)bkt)[tid];
  unsigned int wsg[4] = {wv.x, wv.y, wv.z, wv.w};
  #pragma unroll
  for (int k = 0; k < 16; ++k) {
    int b = (wsg[k >> 2] >> ((k & 3) * 8)) & 63;
    cnt[b][tid]++;
  }
  __syncthreads();
  if (tid < 64) {
    const int b = tid;
    unsigned int run = 0;
    for (int t = 0; t < 256; ++t) {
      unsigned int c = cnt[b][t];
      cnt[b][t] = (unsigned short)run;
      run += c;
    }
    unsigned int incl = run;
    #pragma unroll
    for (int off = 1; off < 64; off <<= 1) {
      unsigned int up = (unsigned int)__shfl_up((int)incl, off);
      if (tid >= off) incl += up;
    }
    bstart[b] = incl - run;
  }
  __syncthreads();
  const int n = nr >> 1, r = nr & 1;
  unsigned int* dst = st + (size_t)n * 8192 + (size_t)r * 4096;
  #pragma unroll
  for (int k = 0; k < 16; ++k) {
    int b = (wsg[k >> 2] >> ((k & 3) * 8)) & 63;
    unsigned int idx = bstart[b] + cnt[b][tid];
    cnt[b][tid]++;
    dst[idx] = (unsigned int)(tid * 16 + k);
  }
}

// ---------------- MFMA chunked local attention (f16 qk gather) ----------------
__global__ __launch_bounds__(256)
void lsh_attn_mfma(const _Float16* __restrict__ qkh, const _Float16* __restrict__ vh,
                   const unsigned int* __restrict__ st,
                   _Float16* __restrict__ o, float* __restrict__ logits) {
  __shared__ _Float16 Kl[128 * 64];
  __shared__ _Float16 Vt[64 * 128];
  __shared__ _Float16 Pl[64 * 128];
  __shared__ float rsqs[128];
  __shared__ float partial[256];
  __shared__ int posl[128];

  const int tid = threadIdx.x;
  const int lane = tid & 63, wid = tid >> 6;
  const int fr = lane & 15, g = lane >> 4;
  const int c = blockIdx.x, n = blockIdx.y;
  const int cprev = (c + 127) & 127;

  if (tid < 128) {
    int p = (tid < 64) ? (c * 64 + tid) : (cprev * 64 + (tid - 64));
    posl[tid] = (int)st[(size_t)n * 8192 + p];
  }
  __syncthreads();

  {
    const int j = tid >> 1, h = tid & 1;
    const int gpos = posl[j];
    const f16x8* srcK = (const f16x8*)(qkh + ((size_t)n * L_SEQ + gpos) * 64 + h * 32);
    const f16x8* srcV = (const f16x8*)(vh + ((size_t)n * L_SEQ + gpos) * 64 + h * 32);
    float ss = 0.f;
    #pragma unroll
    for (int i = 0; i < 4; ++i) {
      f16x8 kv = srcK[i];
      f16x8 vv4 = srcV[i];
      #pragma unroll
      for (int e = 0; e < 8; ++e) {
        float xv = (float)kv[e];
        ss += xv * xv;
        int d = h * 32 + i * 8 + e;
        Vt[d * 128 + (j ^ ((d & 7) << 3))] = vv4[e];
      }
      int ch = h * 4 + i;
      *(f16x8*)(&Kl[j * 64 + ((ch ^ (j & 7)) * 8)]) = kv;
    }
    partial[tid] = ss;
  }
  __syncthreads();
  if (tid < 128)
    rsqs[tid] = rsqrtf(fmaxf(partial[tid * 2] + partial[tid * 2 + 1], 1e-12f));
  __syncthreads();

  const int q0 = wid * 16;
  f32x4 acc[8];
  #pragma unroll
  for (int t = 0; t < 8; ++t) acc[t] = (f32x4){0.f, 0.f, 0.f, 0.f};
  f16x8 aq[2];
  #pragma unroll
  for (int ks = 0; ks < 2; ++ks)
    aq[ks] = *(const f16x8*)&Kl[(q0 + fr) * 64 + (((ks * 4 + g) ^ (fr & 7)) * 8)];
  #pragma unroll
  for (int t = 0; t < 8; ++t) {
    #pragma unroll
    for (int ks = 0; ks < 2; ++ks) {
      f16x8 bk = *(const f16x8*)&Kl[(t * 16 + fr) * 64 + (((ks * 4 + g) ^ (fr & 7)) * 8)];
      acc[t] = __builtin_amdgcn_mfma_f32_16x16x32_f16(aq[ks], bk, acc[t], 0, 0, 0);
    }
  }

  float sc[8][4];
  int pq[4];
  #pragma unroll
  for (int r = 0; r < 4; ++r) pq[r] = posl[q0 + g * 4 + r];
  #pragma unroll
  for (int t = 0; t < 8; ++t) {
    float rs = rsqs[t * 16 + fr] * 0.125f;
    int pk = posl[t * 16 + fr];
    #pragma unroll
    for (int r = 0; r < 4; ++r) {
      float v_ = acc[t][r] * rs;
      if (pq[r] == pk) v_ += -1e5f;
      sc[t][r] = v_;
    }
  }
  float lsef[4];
  #pragma unroll
  for (int r = 0; r < 4; ++r) {
    float m = sc[0][r];
    #pragma unroll
    for (int t = 1; t < 8; ++t) m = fmaxf(m, sc[t][r]);
    #pragma unroll
    for (int off = 1; off < 16; off <<= 1) m = fmaxf(m, __shfl_xor(m, off, 64));
    float s = 0.f;
    #pragma unroll
    for (int t = 0; t < 8; ++t) { float e = __expf(sc[t][r] - m); sc[t][r] = e; s += e; }
    #pragma unroll
    for (int off = 1; off < 16; off <<= 1) s += __shfl_xor(s, off, 64);
    lsef[r] = m + __logf(s);
    float f = 1.0f / s;
    #pragma unroll
    for (int t = 0; t < 8; ++t) sc[t][r] *= f;
  }

  #pragma unroll
  for (int t = 0; t < 8; ++t)
    #pragma unroll
    for (int r = 0; r < 4; ++r) {
      int q = q0 + g * 4 + r;
      Pl[q * 128 + ((t * 16 + fr) ^ ((q & 7) << 3))] = (_Float16)sc[t][r];
    }
  const int rr = c >> 6;
  if (fr == 0) {
    #pragma unroll
    for (int r = 0; r < 4; ++r) {
      int q = q0 + g * 4 + r;
      logits[((size_t)n * 2 + rr) * L_SEQ + posl[q]] = lsef[r];
    }
  }

  f32x4 acc2[4];
  #pragma unroll
  for (int td = 0; td < 4; ++td) acc2[td] = (f32x4){0.f, 0.f, 0.f, 0.f};
  #pragma unroll
  for (int s = 0; s < 4; ++s) {
    f16x8 ap = *(const f16x8*)&Pl[(q0 + fr) * 128 + (((s * 4 + g) ^ (fr & 7)) * 8)];
    #pragma unroll
    for (int td = 0; td < 4; ++td) {
      f16x8 bv = *(const f16x8*)&Vt[(td * 16 + fr) * 128 + (((s * 4 + g) ^ (fr & 7)) * 8)];
      acc2[td] = __builtin_amdgcn_mfma_f32_16x16x32_f16(ap, bv, acc2[td], 0, 0, 0);
    }
  }
  #pragma unroll
  for (int r = 0; r < 4; ++r) {
    int q = q0 + g * 4 + r;
    size_t base = (((size_t)n * 2 + rr) * L_SEQ + posl[q]) * 64;
    #pragma unroll
    for (int td = 0; td < 4; ++td)
      o[base + td * 16 + fr] = (_Float16)acc2[td][r];
  }
}

// ---------------- combine hash rounds -> f16 att [8192][1024] ----------------
__global__ __launch_bounds__(256)
void lsh_combine(const __half* __restrict__ o, const float* __restrict__ logits,
                 _Float16* __restrict__ attf) {
  size_t gid = (size_t)blockIdx.x * 256 + threadIdx.x;
  int q4 = (int)(gid & 15);
  size_t nl = gid >> 4;
  int n = (int)(nl >> 12), l = (int)(nl & 4095);
  float l0 = logits[((size_t)n * 2 + 0) * L_SEQ + l];
  float l1 = logits[((size_t)n * 2 + 1) * L_SEQ + l];
  float m = fmaxf(l0, l1);
  float e0 = __expf(l0 - m), e1 = __expf(l1 - m);
  float inv = 1.0f / (e0 + e1);
  float w0 = e0 * inv, w1 = e1 * inv;
  const __half2* r0 = (const __half2*)(o + (((size_t)n * 2 + 0) * L_SEQ + l) * 64) + q4 * 2;
  const __half2* r1 = (const __half2*)(o + (((size_t)n * 2 + 1) * L_SEQ + l) * 64) + q4 * 2;
  float2 a0 = __half22float2(r0[0]), a1 = __half22float2(r0[1]);
  float2 b0 = __half22float2(r1[0]), b1 = __half22float2(r1[1]);
  f16x4 res;
  res[0] = (_Float16)(w0 * a0.x + w1 * b0.x);
  res[1] = (_Float16)(w0 * a0.y + w1 * b0.y);
  res[2] = (_Float16)(w0 * a1.x + w1 * b1.x);
  res[3] = (_Float16)(w0 * a1.y + w1 * b1.y);
  int bb = n >> 4, h = n & 15;
  *(f16x4*)(attf + ((size_t)bb * L_SEQ + l) * 1024 + h * 64 + q4 * 4) = res;
}

extern "C" void kernel_launch(void* const* d_in, const int* in_sizes, int n_in,
                              void* d_out, int out_size, void* d_ws, size_t ws_size,
                              hipStream_t stream) {
  const float* x   = (const float*)d_in[0];
  const float* Wqk = (const float*)d_in[2];
  const float* Wv  = (const float*)d_in[3];
  const float* Wo  = (const float*)d_in[4];
  const float* rot = (const float*)d_in[5];
  float* out = (float*)d_out;
  char* ws = (char*)d_ws;

  _Float16*     qkh    = (_Float16*)(ws + 0);                 // 16 MB
  _Float16*     vh     = (_Float16*)(ws + 16777216ull);       // 16 MB
  _Float16*     xh     = (_Float16*)(ws + 33554432ull);       // 16 MB (dead after gemms)
  _Float16*     attf   = (_Float16*)(ws + 33554432ull);       // overlays xh
  _Float16*     o      = (_Float16*)(ws + 50331648ull);       // 32 MB (attn output)
  // pre-attn scratch overlaying the o region:
  unsigned long long* rotbuf = (unsigned long long*)(ws + 50331648ull); // 2 MB
  unsigned int* lists  = (unsigned int*)(ws + 52428800ull);   // 1 MB
  unsigned int* cntp   = (unsigned int*)(ws + 53477376ull);   // 4 KB
  float*        WR     = (float*)(ws + 53481472ull);          // 4 MB
  float*        logits = (float*)(ws + 83886080ull);          // 1 MB
  unsigned int* st     = (unsigned int*)(ws + 84934656ull);   // 1 MB
  unsigned char* bucket = (unsigned char*)(ws + 85983232ull); // 256 KB
  _Float16*     WqkT   = (_Float16*)(ws + 86245376ull);       // 2 MB
  _Float16*     WvT    = (_Float16*)(ws + 88342528ull);       // 2 MB
  _Float16*     WoT    = (_Float16*)(ws + 90439680ull);       // 2 MB

  dim3 gb(256);
  dim3 gemmGrid(512);

  hipMemsetAsync(cntp, 0, 32 * sizeof(unsigned int), stream);
  cvt_f16<<<dim3(8192), gb, 0, stream>>>(x, xh);
  cvt_tr_f16<<<dim3(32, 32), gb, 0, stream>>>(Wqk, WqkT);
  cvt_tr_f16<<<dim3(32, 32), gb, 0, stream>>>(Wv, WvT);
  cvt_tr_f16<<<dim3(32, 32), gb, 0, stream>>>(Wo, WoT);
  wr_precompute<<<dim3(32, 8), gb, 0, stream>>>(Wqk, rot, WR);

  gemm_f16<1><<<gemmGrid, gb, 0, stream>>>(xh, WqkT, (float*)qkh, 8192, 1024, 1024);
  gemm_f16<1><<<gemmGrid, gb, 0, stream>>>(xh, WvT, (float*)vh, 8192, 1024, 1024);

  lsh_hash2<<<dim3(16, 32), gb, 0, stream>>>(qkh, rot, bucket, lists, cntp);
  lsh_fixup<<<dim3(256), gb, 0, stream>>>(x, WR, lists, cntp, rotbuf, bucket);
  lsh_sort<<<dim3(64), gb, 0, stream>>>(bucket, st);
  lsh_attn_mfma<<<dim3(128, 32), gb, 0, stream>>>(qkh, vh, st, o, logits);
  lsh_combine<<<dim3(8192), gb, 0, stream>>>((const __half*)o, logits, attf);

  gemm_f16<0><<<gemmGrid, gb, 0, stream>>>(attf, WoT, out, 8192, 1024, 1024);
}